// Round 4
// baseline (362.170 us; speedup 1.0000x reference)
//
#include <hip/hip_runtime.h>
#include <hip/hip_bf16.h>

// AttnDecoderRNN. B=128, S=400, H=256, E=128, V=50000, PAD=250.
// Inputs: float32 + int32 (per reference dtypes). Outputs: float32.
// Outputs (f32, concat): h_new(B*H), p_final(B*VP), p_gen(B), p_vocab(B*V), att_dist(B*S)

#define B_ 128
#define S_ 400
#define H_ 256
#define E_ 128
#define V_ 50000
#define PAD_ 250
#define VP_ (V_ + PAD_)

typedef unsigned short ushort_t;
typedef __attribute__((ext_vector_type(8))) short bf16x8;
typedef __attribute__((ext_vector_type(4))) float f32x4;

__device__ __forceinline__ unsigned short f2bfu(float f) {
    __hip_bfloat16 h = __float2bfloat16(f);  // RNE
    union { __hip_bfloat16 h; unsigned short u; } c;
    c.h = h;
    return c.u;
}

__device__ __forceinline__ float sigmoid_fast(float x) {
    return 1.0f / (1.0f + __expf(-x));
}

__device__ __forceinline__ float tanh_fast(float x) {
    return 1.0f - 2.0f / (__expf(2.0f * x) + 1.0f);
}

__device__ __forceinline__ float waveReduceSum(float v) {
#pragma unroll
    for (int off = 32; off; off >>= 1) v += __shfl_down(v, off, 64);
    return v;
}

__device__ __forceinline__ float waveReduceMax(float v) {
#pragma unroll
    for (int off = 32; off; off >>= 1) v = fmaxf(v, __shfl_down(v, off, 64));
    return v;
}

// dot(row_f32[0..n), s_f32[0..n)); n % 4 == 0, row 16B-aligned
__device__ __forceinline__ float dot_row_f32(const float* __restrict__ row,
                                             const float* __restrict__ s, int n) {
    float acc = 0.0f;
#pragma unroll 4
    for (int c = 0; c < (n >> 2); c++) {
        float4 q = *(const float4*)(row + c * 4);
        const float* sp = s + c * 4;
        acc += sp[0] * q.x + sp[1] * q.y + sp[2] * q.z + sp[3] * q.w;
    }
    return acc;
}

// ---------------- K1: embedding gather + GRU cell; zero row_sum ----------------
__global__ __launch_bounds__(256) void k_gru(
    const int* __restrict__ token, const float* __restrict__ emb,
    const float* __restrict__ hprev,
    const float* __restrict__ w_ih, const float* __restrict__ w_hh,
    const float* __restrict__ b_ih, const float* __restrict__ b_hh,
    float* __restrict__ x_ws, float* __restrict__ hnew_ws, float* __restrict__ row_sum,
    float* __restrict__ out_hnew) {
    int b = blockIdx.x;
    int t = threadIdx.x;
    __shared__ float xs[E_];
    __shared__ float hs[H_];
    int tok = token[b];
    if (t < E_) {
        float v = emb[(size_t)tok * E_ + t];
        xs[t] = v;
        x_ws[b * E_ + t] = v;
    }
    hs[t] = hprev[b * H_ + t];
    if (t == 0) row_sum[b] = 0.0f;
    __syncthreads();

    float ir = dot_row_f32(w_ih + (size_t)t * E_, xs, E_) + b_ih[t];
    float iz = dot_row_f32(w_ih + (size_t)(t + H_) * E_, xs, E_) + b_ih[t + H_];
    float in_ = dot_row_f32(w_ih + (size_t)(t + 2 * H_) * E_, xs, E_) + b_ih[t + 2 * H_];
    float hr = dot_row_f32(w_hh + (size_t)t * H_, hs, H_) + b_hh[t];
    float hz = dot_row_f32(w_hh + (size_t)(t + H_) * H_, hs, H_) + b_hh[t + H_];
    float hn = dot_row_f32(w_hh + (size_t)(t + 2 * H_) * H_, hs, H_) + b_hh[t + 2 * H_];

    float r = sigmoid_fast(ir + hr);
    float z = sigmoid_fast(iz + hz);
    float n = tanh_fast(in_ + r * hn);
    float h = (1.0f - z) * n + z * hs[t];
    hnew_ws[b * H_ + t] = h;
    out_hnew[b * H_ + t] = h;
}

// ---------------- K2: attention scores + softmax + context ----------------
__global__ __launch_bounds__(256) void k_attn(
    const float* __restrict__ enc,
    const float* __restrict__ w_h, const float* __restrict__ w_s,
    const float* __restrict__ att_bias, const float* __restrict__ attn_v,
    const float* __restrict__ hnew_ws,
    float* __restrict__ attd_ws, float* __restrict__ ctx_ws,
    float* __restrict__ out_attd) {
    int b = blockIdx.x;
    int t = threadIdx.x;
    __shared__ float cs[H_], whs[H_], vs[H_];
    __shared__ float sc[S_];
    __shared__ float red[8];
    float bias = att_bias[0];
    whs[t] = w_h[t];
    vs[t] = attn_v[t];
    cs[t] = w_s[t] * hnew_ws[b * H_ + t] + bias;
    __syncthreads();

    int wave = t >> 6, lane = t & 63;
    for (int s = wave; s < S_; s += 4) {
        const float* ep = enc + ((size_t)(b * S_ + s)) * H_ + lane * 4;
        float4 u = *(const float4*)ep;
        int h0 = lane * 4;
        float p = vs[h0 + 0] * tanh_fast(whs[h0 + 0] * u.x + cs[h0 + 0])
                + vs[h0 + 1] * tanh_fast(whs[h0 + 1] * u.y + cs[h0 + 1])
                + vs[h0 + 2] * tanh_fast(whs[h0 + 2] * u.z + cs[h0 + 2])
                + vs[h0 + 3] * tanh_fast(whs[h0 + 3] * u.w + cs[h0 + 3]);
        p = waveReduceSum(p);
        if (lane == 0) sc[s] = p;
    }
    __syncthreads();

    float m = -1e30f;
    for (int s = t; s < S_; s += 256) m = fmaxf(m, sc[s]);
    m = waveReduceMax(m);
    if (lane == 0) red[wave] = m;
    __syncthreads();
    m = fmaxf(fmaxf(red[0], red[1]), fmaxf(red[2], red[3]));
    float ssum = 0.0f;
    for (int s = t; s < S_; s += 256) {
        float e = __expf(sc[s] - m);
        sc[s] = e;
        ssum += e;
    }
    ssum = waveReduceSum(ssum);
    if (lane == 0) red[4 + wave] = ssum;
    __syncthreads();
    float inv = 1.0f / (red[4] + red[5] + red[6] + red[7]);
    for (int s = t; s < S_; s += 256) {
        float a = sc[s] * inv;
        sc[s] = a;
        attd_ws[b * S_ + s] = a;
        out_attd[b * S_ + s] = a;
    }
    __syncthreads();

    float acc = 0.0f;
    const float* ep = enc + (size_t)b * S_ * H_ + t;
    for (int s = 0; s < S_; s++) acc += sc[s] * ep[s * H_];
    ctx_ws[b * H_ + t] = acc;
}

// ---------------- K3: hidden = dec_ctx @ outh_w^T + outh_b; p_gen ----------------
__global__ __launch_bounds__(128) void k_outh(
    const float* __restrict__ outh_w, const float* __restrict__ outh_b,
    const float* __restrict__ gen_w, const float* __restrict__ gen_b,
    const float* __restrict__ hnew_ws, const float* __restrict__ ctx_ws,
    const float* __restrict__ x_ws,
    float* __restrict__ hidden_ws, float* __restrict__ pgen_ws,
    float* __restrict__ out_pgen) {
    int b = blockIdx.x;
    int t = threadIdx.x;  // 128
    __shared__ float dc[2 * H_ + E_];  // [h_new(256), context(256), x(128)]
    __shared__ float r2[2];
    dc[t] = hnew_ws[b * H_ + t];
    dc[t + 128] = hnew_ws[b * H_ + t + 128];
    dc[256 + t] = ctx_ws[b * H_ + t];
    dc[384 + t] = ctx_ws[b * H_ + t + 128];
    dc[512 + t] = x_ws[b * E_ + t];
    __syncthreads();

    float acc = dot_row_f32(outh_w + (size_t)t * (2 * H_), dc, 2 * H_) + outh_b[t];
    hidden_ws[b * E_ + t] = acc;

    float pp = 0.0f;
    for (int k = t; k < 2 * H_ + E_; k += 128) pp += dc[k] * gen_w[k];
    pp = waveReduceSum(pp);
    if ((t & 63) == 0) r2[t >> 6] = pp;
    __syncthreads();
    if (t == 0) {
        float g = sigmoid_fast(r2[0] + r2[1] + gen_b[0]);
        pgen_ws[b] = g;
        out_pgen[b] = g;
    }
}

// ---------------- K4: vocab GEMM (MFMA bf16) -> exp (f32 into p_vocab) + row sums ----
// Grid: 196 blocks x 256 thr. Block handles 16 v-tiles of 16 rows (4 per wave), all 128 b.
// A = hidden[b][k] (bf16 in LDS), B^T = outv_w[v][k] (f32 rows, cvt to bf16 per fragment).
// mfma_f32_16x16x32_bf16: A/B frag: m(or n)=lane&15, k=quad*8+j. D: row=quad*4+reg, col=lane&15.
#define VT_TOTAL (V_ / 16)          // 3125 exactly
#define HID_PITCH 136               // 128 + 8 pad shorts: rows 16B-aligned, 2-way bank alias (free)
__global__ __launch_bounds__(256) void k_vocab_mfma(
    const float* __restrict__ outv_w, const float* __restrict__ outv_b,
    const float* __restrict__ hidden_ws,
    float* __restrict__ out_pvocab, float* __restrict__ row_sum) {
    __shared__ ushort_t hid[B_ * HID_PITCH];   // 34816 B
    __shared__ float rsum[B_];
    int t = threadIdx.x;

    // stage hidden (128x128 f32) -> bf16 LDS
    const float4* h4 = (const float4*)hidden_ws;
#pragma unroll
    for (int i = 0; i < 16; i++) {
        int fidx = i * 256 + t;            // float4 index, [0,4096)
        float4 q = h4[fidx];
        int row = fidx >> 5;               // 32 float4 per row of 128
        int col = (fidx & 31) << 2;
        ushort4 u;
        u.x = f2bfu(q.x); u.y = f2bfu(q.y); u.z = f2bfu(q.z); u.w = f2bfu(q.w);
        *(ushort4*)&hid[row * HID_PITCH + col] = u;
    }
    if (t < B_) rsum[t] = 0.0f;
    __syncthreads();

    int wave = t >> 6, lane = t & 63;
    int lm = lane & 15, quad = lane >> 4;

#pragma unroll 1
    for (int i = 0; i < 4; i++) {
        int vt = blockIdx.x * 16 + i * 4 + wave;
        if (vt >= VT_TOTAL) continue;      // wave-uniform
        int v = vt * 16 + lm;
        const float* wrow = outv_w + (size_t)v * E_;

        f32x4 acc[8];
#pragma unroll
        for (int bt = 0; bt < 8; bt++) acc[bt] = (f32x4){0.f, 0.f, 0.f, 0.f};

#pragma unroll
        for (int kc = 0; kc < 4; kc++) {
            int k0 = kc * 32 + quad * 8;
            float4 w0 = *(const float4*)(wrow + k0);
            float4 w1 = *(const float4*)(wrow + k0 + 4);
            bf16x8 bf;
            bf[0] = (short)f2bfu(w0.x); bf[1] = (short)f2bfu(w0.y);
            bf[2] = (short)f2bfu(w0.z); bf[3] = (short)f2bfu(w0.w);
            bf[4] = (short)f2bfu(w1.x); bf[5] = (short)f2bfu(w1.y);
            bf[6] = (short)f2bfu(w1.z); bf[7] = (short)f2bfu(w1.w);
#pragma unroll
            for (int bt = 0; bt < 8; bt++) {
                bf16x8 af = *(const bf16x8*)&hid[(bt * 16 + lm) * HID_PITCH + k0];
                acc[bt] = __builtin_amdgcn_mfma_f32_16x16x32_bf16(af, bf, acc[bt], 0, 0, 0);
            }
        }

        float bias = outv_b[v];
#pragma unroll
        for (int bt = 0; bt < 8; bt++) {
#pragma unroll
            for (int r = 0; r < 4; r++) {
                int b = bt * 16 + quad * 4 + r;
                float e = __expf(fminf(acc[bt][r] + bias, 60.0f));
                out_pvocab[(size_t)b * V_ + v] = e;
                float s = e;
                s += __shfl_xor(s, 1);
                s += __shfl_xor(s, 2);
                s += __shfl_xor(s, 4);
                s += __shfl_xor(s, 8);
                if (lm == 0) atomicAdd(&rsum[b], s);
            }
        }
    }
    __syncthreads();
    if (t < B_) atomicAdd(&row_sum[t], rsum[t]);
}

// ---------------- K5: normalize in-place: p_vocab, p_final dense + PAD zeros --------
__global__ __launch_bounds__(256) void k_final(
    const float* __restrict__ row_sum, const float* __restrict__ pgen_ws,
    float* __restrict__ out_pfinal, float* __restrict__ out_pvocab) {
    int b = blockIdx.y;
    int jbase = blockIdx.x * 2048;
    int t = threadIdx.x;
    float inv = 1.0f / row_sum[b];
    float pg = pgen_ws[b];
#pragma unroll
    for (int i = 0; i < 8; i++) {
        int j = jbase + i * 256 + t;
        if (j < VP_) {
            if (j < V_) {
                float p = out_pvocab[(size_t)b * V_ + j] * inv;
                out_pvocab[(size_t)b * V_ + j] = p;
                out_pfinal[(size_t)b * VP_ + j] = p * pg;
            } else {
                out_pfinal[(size_t)b * VP_ + j] = 0.0f;
            }
        }
    }
}

// ---------------- K6: scatter-add (1-p_gen)*att_dist into p_final ----------------
__global__ __launch_bounds__(256) void k_scatter(
    const int* __restrict__ fiv, const float* __restrict__ attd_ws,
    const float* __restrict__ pgen_ws, float* __restrict__ out_pfinal) {
    int b = blockIdx.x;
    int t = threadIdx.x;
    float omg = 1.0f - pgen_ws[b];
    for (int s = t; s < S_; s += 256) {
        int idx = fiv[b * S_ + s];
        float val = omg * attd_ws[b * S_ + s];
        atomicAdd(&out_pfinal[(size_t)b * VP_ + idx], val);
    }
}

extern "C" void kernel_launch(void* const* d_in, const int* in_sizes, int n_in,
                              void* d_out, int out_size, void* d_ws, size_t ws_size,
                              hipStream_t stream) {
    const int* token = (const int*)d_in[0];
    const float* hprev = (const float*)d_in[1];
    const float* enc = (const float*)d_in[2];
    const int* fiv = (const int*)d_in[3];
    const float* emb = (const float*)d_in[4];
    const float* w_ih = (const float*)d_in[5];
    const float* w_hh = (const float*)d_in[6];
    const float* b_ih = (const float*)d_in[7];
    const float* b_hh = (const float*)d_in[8];
    const float* w_h = (const float*)d_in[9];
    const float* w_s = (const float*)d_in[10];
    const float* att_bias = (const float*)d_in[11];
    const float* attn_v = (const float*)d_in[12];
    const float* gen_w = (const float*)d_in[13];
    const float* gen_b = (const float*)d_in[14];
    const float* outh_w = (const float*)d_in[15];
    const float* outh_b = (const float*)d_in[16];
    const float* outv_w = (const float*)d_in[17];
    const float* outv_b = (const float*)d_in[18];

    float* out = (float*)d_out;
    float* out_hnew = out;                                    // B*H
    float* out_pfinal = out + (size_t)B_ * H_;                // B*VP
    float* out_pgen = out_pfinal + (size_t)B_ * VP_;          // B
    float* out_pvocab = out_pgen + B_;                        // B*V
    float* out_attd = out_pvocab + (size_t)B_ * V_;           // B*S

    float* wsf = (float*)d_ws;
    float* x_ws = wsf;                       // 16384
    float* hnew_ws = wsf + 16384;            // 32768
    float* attd_ws = wsf + 49152;            // 51200
    float* ctx_ws = wsf + 100352;            // 32768
    float* hidden_ws = wsf + 133120;         // 16384
    float* pgen_ws = wsf + 149504;           // 128
    float* row_sum = wsf + 149632;           // 128  (total ~599 KB)

    k_gru<<<B_, 256, 0, stream>>>(token, emb, hprev, w_ih, w_hh, b_ih, b_hh,
                                  x_ws, hnew_ws, row_sum, out_hnew);
    k_attn<<<B_, 256, 0, stream>>>(enc, w_h, w_s, att_bias, attn_v, hnew_ws,
                                   attd_ws, ctx_ws, out_attd);
    k_outh<<<B_, 128, 0, stream>>>(outh_w, outh_b, gen_w, gen_b,
                                   hnew_ws, ctx_ws, x_ws, hidden_ws, pgen_ws, out_pgen);
    k_vocab_mfma<<<196, 256, 0, stream>>>(outv_w, outv_b, hidden_ws, out_pvocab, row_sum);
    k_final<<<dim3(25, B_), 256, 0, stream>>>(row_sum, pgen_ws, out_pfinal, out_pvocab);
    k_scatter<<<B_, 256, 0, stream>>>(fiv, attd_ws, pgen_ws, out_pfinal);
}

// Round 5
// 253.531 us; speedup vs baseline: 1.4285x; 1.4285x over previous
//
#include <hip/hip_runtime.h>
#include <hip/hip_bf16.h>

// AttnDecoderRNN. B=128, S=400, H=256, E=128, V=50000, PAD=250.
// Inputs: float32 + int32. Outputs: float32 concat:
//   h_new(B*H), p_final(B*VP), p_gen(B), p_vocab(B*V), att_dist(B*S)

#define B_ 128
#define S_ 400
#define H_ 256
#define E_ 128
#define V_ 50000
#define PAD_ 250
#define VP_ (V_ + PAD_)
#define NC_ 8            // attention S-chunks
#define CS_ (S_ / NC_)   // 50

typedef unsigned short ushort_t;
typedef __attribute__((ext_vector_type(8))) short bf16x8;
typedef __attribute__((ext_vector_type(4))) float f32x4;

__device__ __forceinline__ unsigned short f2bfu(float f) {
    __hip_bfloat16 h = __float2bfloat16(f);  // RNE
    union { __hip_bfloat16 h; unsigned short u; } c;
    c.h = h;
    return c.u;
}

__device__ __forceinline__ float sigmoid_fast(float x) {
    return 1.0f / (1.0f + __expf(-x));
}

__device__ __forceinline__ float tanh_fast(float x) {
    return 1.0f - 2.0f / (__expf(2.0f * x) + 1.0f);
}

__device__ __forceinline__ float waveReduceSum(float v) {
#pragma unroll
    for (int off = 32; off; off >>= 1) v += __shfl_down(v, off, 64);
    return v;
}

__device__ __forceinline__ float waveReduceSumAll(float v) {
#pragma unroll
    for (int off = 1; off < 64; off <<= 1) v += __shfl_xor(v, off, 64);
    return v;
}

// dot(row_f32[0..n), s_f32[0..n)); n % 4 == 0, row 16B-aligned
__device__ __forceinline__ float dot_row_f32(const float* __restrict__ row,
                                             const float* __restrict__ s, int n) {
    float acc = 0.0f;
#pragma unroll 4
    for (int c = 0; c < (n >> 2); c++) {
        float4 q = *(const float4*)(row + c * 4);
        const float* sp = s + c * 4;
        acc += sp[0] * q.x + sp[1] * q.y + sp[2] * q.z + sp[3] * q.w;
    }
    return acc;
}

// ---------- K1: GRU gates GEMM via MFMA: gi = x@w_ih^T, gh = h@w_hh^T ----------
// A = [x(K=128) | h(K=256)] bf16 in LDS. 96 v-tiles of 16 cols: vt<48 -> gi, else gh.
// Grid 24 x 256 (1 v-tile per wave).
#define XH_PITCH 392   // 384 + 8 shorts; row stride 784 B (16B-aligned, 2-way bank alias = free)
__global__ __launch_bounds__(256) void k_gates(
    const int* __restrict__ token, const float* __restrict__ emb,
    const float* __restrict__ hprev,
    const float* __restrict__ w_ih, const float* __restrict__ w_hh,
    float* __restrict__ x_ws, float* __restrict__ gi_ws, float* __restrict__ gh_ws) {
    __shared__ ushort_t xh[B_ * XH_PITCH];   // 100352 B
    __shared__ int toks[B_];
    int t = threadIdx.x;
    if (t < B_) toks[t] = token[t];
    __syncthreads();
    // stage x (gather) : 128 rows x 32 float4
#pragma unroll
    for (int i = 0; i < 16; i++) {
        int fidx = i * 256 + t;
        int b = fidx >> 5, k4 = fidx & 31;
        float4 q = *(const float4*)(emb + (size_t)toks[b] * E_ + k4 * 4);
        ushort4 u;
        u.x = f2bfu(q.x); u.y = f2bfu(q.y); u.z = f2bfu(q.z); u.w = f2bfu(q.w);
        *(ushort4*)&xh[b * XH_PITCH + k4 * 4] = u;
        *(float4*)(x_ws + b * E_ + k4 * 4) = q;
    }
    // stage h : 128 rows x 64 float4
#pragma unroll
    for (int i = 0; i < 32; i++) {
        int fidx = i * 256 + t;
        int b = fidx >> 6, k4 = fidx & 63;
        float4 q = *(const float4*)(hprev + (size_t)b * H_ + k4 * 4);
        ushort4 u;
        u.x = f2bfu(q.x); u.y = f2bfu(q.y); u.z = f2bfu(q.z); u.w = f2bfu(q.w);
        *(ushort4*)&xh[b * XH_PITCH + 128 + k4 * 4] = u;
    }
    __syncthreads();

    int wave = t >> 6, lane = t & 63, lm = lane & 15, quad = lane >> 4;
    int vt = blockIdx.x * 4 + wave;          // 0..95
    bool isIH = vt < 48;
    int n0 = (isIH ? vt : vt - 48) * 16;
    const float* wbase = isIH ? w_ih : w_hh;
    int K = isIH ? E_ : H_;
    int aoff = isIH ? 0 : 128;
    float* gout = isIH ? gi_ws : gh_ws;
    int v = n0 + lm;
    const float* wrow = wbase + (size_t)v * K;

    f32x4 acc[8];
#pragma unroll
    for (int bt = 0; bt < 8; bt++) acc[bt] = (f32x4){0.f, 0.f, 0.f, 0.f};

    for (int kc = 0; kc < (K >> 5); kc++) {
        int k0 = kc * 32 + quad * 8;
        float4 w0 = *(const float4*)(wrow + k0);
        float4 w1 = *(const float4*)(wrow + k0 + 4);
        bf16x8 bf;
        bf[0] = (short)f2bfu(w0.x); bf[1] = (short)f2bfu(w0.y);
        bf[2] = (short)f2bfu(w0.z); bf[3] = (short)f2bfu(w0.w);
        bf[4] = (short)f2bfu(w1.x); bf[5] = (short)f2bfu(w1.y);
        bf[6] = (short)f2bfu(w1.z); bf[7] = (short)f2bfu(w1.w);
#pragma unroll
        for (int bt = 0; bt < 8; bt++) {
            bf16x8 af = *(const bf16x8*)&xh[(bt * 16 + lm) * XH_PITCH + aoff + k0];
            acc[bt] = __builtin_amdgcn_mfma_f32_16x16x32_bf16(af, bf, acc[bt], 0, 0, 0);
        }
    }
#pragma unroll
    for (int bt = 0; bt < 8; bt++)
#pragma unroll
        for (int r = 0; r < 4; r++) {
            int b = bt * 16 + quad * 4 + r;
            gout[(size_t)b * 768 + v] = acc[bt][r];
        }
}

// ---------- K2: GRU nonlinearity; also zero row_sum ----------
__global__ __launch_bounds__(256) void k_gru_nl(
    const float* __restrict__ gi_ws, const float* __restrict__ gh_ws,
    const float* __restrict__ b_ih, const float* __restrict__ b_hh,
    const float* __restrict__ hprev,
    float* __restrict__ hnew_ws, float* __restrict__ row_sum,
    float* __restrict__ out_hnew) {
    int b = blockIdx.x;
    int t = threadIdx.x;
    float ir = gi_ws[(size_t)b * 768 + t] + b_ih[t];
    float iz = gi_ws[(size_t)b * 768 + 256 + t] + b_ih[256 + t];
    float in_ = gi_ws[(size_t)b * 768 + 512 + t] + b_ih[512 + t];
    float hr = gh_ws[(size_t)b * 768 + t] + b_hh[t];
    float hz = gh_ws[(size_t)b * 768 + 256 + t] + b_hh[256 + t];
    float hn = gh_ws[(size_t)b * 768 + 512 + t] + b_hh[512 + t];
    float hp = hprev[(size_t)b * H_ + t];
    float r = sigmoid_fast(ir + hr);
    float z = sigmoid_fast(iz + hz);
    float n = tanh_fast(in_ + r * hn);
    float h = (1.0f - z) * n + z * hp;
    hnew_ws[b * H_ + t] = h;
    out_hnew[b * H_ + t] = h;
    if (t == 0) row_sum[b] = 0.0f;
}

// ---------- K3a: attention scores + online-softmax context partials ----------
// Grid (NC_, B_) x 256. Each block: one (b, s-chunk). Single pass over enc.
__global__ __launch_bounds__(256) void k_attn_scores(
    const float* __restrict__ enc,
    const float* __restrict__ w_h, const float* __restrict__ w_s,
    const float* __restrict__ att_bias, const float* __restrict__ attn_v,
    const float* __restrict__ hnew_ws,
    float* __restrict__ sc_ws, float* __restrict__ ml_ws, float* __restrict__ ctxp_ws) {
    int c = blockIdx.x, b = blockIdx.y;
    int t = threadIdx.x;
    __shared__ float cs[H_], whs[H_], vs[H_];
    __shared__ float cmerge[H_];
    __shared__ float mred[4], lred[4];
    float bias = att_bias[0];
    whs[t] = w_h[t];
    vs[t] = attn_v[t];
    cs[t] = w_s[t] * hnew_ws[b * H_ + t] + bias;
    cmerge[t] = 0.0f;
    __syncthreads();

    int wave = t >> 6, lane = t & 63;
    int h0 = lane * 4;
    float m_w = -1e30f, l_w = 0.0f;
    float cx0 = 0.f, cx1 = 0.f, cx2 = 0.f, cx3 = 0.f;

    for (int si = wave; si < CS_; si += 4) {
        int s = c * CS_ + si;
        float4 u = *(const float4*)(enc + ((size_t)(b * S_ + s)) * H_ + h0);
        float p = vs[h0 + 0] * tanh_fast(whs[h0 + 0] * u.x + cs[h0 + 0])
                + vs[h0 + 1] * tanh_fast(whs[h0 + 1] * u.y + cs[h0 + 1])
                + vs[h0 + 2] * tanh_fast(whs[h0 + 2] * u.z + cs[h0 + 2])
                + vs[h0 + 3] * tanh_fast(whs[h0 + 3] * u.w + cs[h0 + 3]);
        p = waveReduceSumAll(p);
        if (lane == 0) sc_ws[b * S_ + s] = p;
        float mn = fmaxf(m_w, p);
        float scale = __expf(m_w - mn);
        float w = __expf(p - mn);
        cx0 = cx0 * scale + w * u.x;
        cx1 = cx1 * scale + w * u.y;
        cx2 = cx2 * scale + w * u.z;
        cx3 = cx3 * scale + w * u.w;
        l_w = l_w * scale + w;
        m_w = mn;
    }
    if (lane == 0) mred[wave] = m_w;
    __syncthreads();
    float m_c = fmaxf(fmaxf(mred[0], mred[1]), fmaxf(mred[2], mred[3]));
    float wf = __expf(m_w - m_c);
    if (lane == 0) lred[wave] = l_w * wf;
    atomicAdd(&cmerge[h0 + 0], cx0 * wf);
    atomicAdd(&cmerge[h0 + 1], cx1 * wf);
    atomicAdd(&cmerge[h0 + 2], cx2 * wf);
    atomicAdd(&cmerge[h0 + 3], cx3 * wf);
    __syncthreads();
    if (t == 0) {
        ml_ws[(b * NC_ + c) * 2 + 0] = m_c;
        ml_ws[(b * NC_ + c) * 2 + 1] = lred[0] + lred[1] + lred[2] + lred[3];
    }
    ctxp_ws[(size_t)(b * NC_ + c) * H_ + t] = cmerge[t];
}

// ---------- K3b: combine chunk partials -> ctx, att_dist ----------
__global__ __launch_bounds__(256) void k_attn_combine(
    const float* __restrict__ sc_ws, const float* __restrict__ ml_ws,
    const float* __restrict__ ctxp_ws,
    float* __restrict__ attd_ws, float* __restrict__ ctx_ws,
    float* __restrict__ out_attd) {
    int b = blockIdx.x;
    int t = threadIdx.x;
    __shared__ float ml[NC_ * 2];
    if (t < NC_ * 2) ml[t] = ml_ws[b * NC_ * 2 + t];
    __syncthreads();
    float M = -1e30f;
#pragma unroll
    for (int c = 0; c < NC_; c++) M = fmaxf(M, ml[2 * c]);
    float L = 0.0f;
#pragma unroll
    for (int c = 0; c < NC_; c++) L += ml[2 * c + 1] * __expf(ml[2 * c] - M);
    float invL = 1.0f / L;

    float acc = 0.0f;
#pragma unroll
    for (int c = 0; c < NC_; c++)
        acc += __expf(ml[2 * c] - M) * ctxp_ws[(size_t)(b * NC_ + c) * H_ + t];
    ctx_ws[b * H_ + t] = acc * invL;

    for (int s = t; s < S_; s += 256) {
        float a = __expf(sc_ws[b * S_ + s] - M) * invL;
        attd_ws[b * S_ + s] = a;
        out_attd[b * S_ + s] = a;
    }
}

// ---------- K4: hidden = dec_ctx @ outh_w^T + outh_b; p_gen ----------
__global__ __launch_bounds__(128) void k_outh(
    const float* __restrict__ outh_w, const float* __restrict__ outh_b,
    const float* __restrict__ gen_w, const float* __restrict__ gen_b,
    const float* __restrict__ hnew_ws, const float* __restrict__ ctx_ws,
    const float* __restrict__ x_ws,
    float* __restrict__ hidden_ws, float* __restrict__ pgen_ws,
    float* __restrict__ out_pgen) {
    int b = blockIdx.x;
    int t = threadIdx.x;  // 128
    __shared__ float dc[2 * H_ + E_];
    __shared__ float r2[2];
    dc[t] = hnew_ws[b * H_ + t];
    dc[t + 128] = hnew_ws[b * H_ + t + 128];
    dc[256 + t] = ctx_ws[b * H_ + t];
    dc[384 + t] = ctx_ws[b * H_ + t + 128];
    dc[512 + t] = x_ws[b * E_ + t];
    __syncthreads();

    float acc = dot_row_f32(outh_w + (size_t)t * (2 * H_), dc, 2 * H_) + outh_b[t];
    hidden_ws[b * E_ + t] = acc;

    float pp = 0.0f;
    for (int k = t; k < 2 * H_ + E_; k += 128) pp += dc[k] * gen_w[k];
    pp = waveReduceSum(pp);
    if ((t & 63) == 0) r2[t >> 6] = pp;
    __syncthreads();
    if (t == 0) {
        float g = sigmoid_fast(r2[0] + r2[1] + gen_b[0]);
        pgen_ws[b] = g;
        out_pgen[b] = g;
    }
}

// ---------- K5: vocab GEMM (MFMA bf16) -> exp (f32 into p_vocab) + row sums ----------
// Grid 782 x 256: 1 v-tile (16 vocab rows) per wave, all 128 b per tile.
#define VT_TOTAL (V_ / 16)          // 3125
#define HID_PITCH 136               // 128+8 shorts
__global__ __launch_bounds__(256) void k_vocab_mfma(
    const float* __restrict__ outv_w, const float* __restrict__ outv_b,
    const float* __restrict__ hidden_ws,
    float* __restrict__ out_pvocab, float* __restrict__ row_sum) {
    __shared__ ushort_t hid[B_ * HID_PITCH];   // 34816 B
    __shared__ float rsum[B_];
    int t = threadIdx.x;

    const float4* h4 = (const float4*)hidden_ws;
#pragma unroll
    for (int i = 0; i < 16; i++) {
        int fidx = i * 256 + t;
        float4 q = h4[fidx];
        int row = fidx >> 5;
        int col = (fidx & 31) << 2;
        ushort4 u;
        u.x = f2bfu(q.x); u.y = f2bfu(q.y); u.z = f2bfu(q.z); u.w = f2bfu(q.w);
        *(ushort4*)&hid[row * HID_PITCH + col] = u;
    }
    if (t < B_) rsum[t] = 0.0f;
    __syncthreads();

    int wave = t >> 6, lane = t & 63, lm = lane & 15, quad = lane >> 4;
    int vt = blockIdx.x * 4 + wave;

    if (vt < VT_TOTAL) {
        int v = vt * 16 + lm;
        const float* wrow = outv_w + (size_t)v * E_;

        f32x4 acc[8];
#pragma unroll
        for (int bt = 0; bt < 8; bt++) acc[bt] = (f32x4){0.f, 0.f, 0.f, 0.f};

#pragma unroll
        for (int kc = 0; kc < 4; kc++) {
            int k0 = kc * 32 + quad * 8;
            float4 w0 = *(const float4*)(wrow + k0);
            float4 w1 = *(const float4*)(wrow + k0 + 4);
            bf16x8 bf;
            bf[0] = (short)f2bfu(w0.x); bf[1] = (short)f2bfu(w0.y);
            bf[2] = (short)f2bfu(w0.z); bf[3] = (short)f2bfu(w0.w);
            bf[4] = (short)f2bfu(w1.x); bf[5] = (short)f2bfu(w1.y);
            bf[6] = (short)f2bfu(w1.z); bf[7] = (short)f2bfu(w1.w);
#pragma unroll
            for (int bt = 0; bt < 8; bt++) {
                bf16x8 af = *(const bf16x8*)&hid[(bt * 16 + lm) * HID_PITCH + k0];
                acc[bt] = __builtin_amdgcn_mfma_f32_16x16x32_bf16(af, bf, acc[bt], 0, 0, 0);
            }
        }

        float bias = outv_b[v];
#pragma unroll
        for (int bt = 0; bt < 8; bt++) {
#pragma unroll
            for (int r = 0; r < 4; r++) {
                int b = bt * 16 + quad * 4 + r;
                float e = __expf(fminf(acc[bt][r] + bias, 60.0f));
                out_pvocab[(size_t)b * V_ + v] = e;
                float s = e;
                s += __shfl_xor(s, 1);
                s += __shfl_xor(s, 2);
                s += __shfl_xor(s, 4);
                s += __shfl_xor(s, 8);
                if (lm == 0) atomicAdd(&rsum[b], s);
            }
        }
    }
    __syncthreads();
    if (t < B_) atomicAdd(&row_sum[t], rsum[t]);
}

// ---------- K6: normalize in-place: p_vocab, p_final dense + PAD zeros ----------
__global__ __launch_bounds__(256) void k_final(
    const float* __restrict__ row_sum, const float* __restrict__ pgen_ws,
    float* __restrict__ out_pfinal, float* __restrict__ out_pvocab) {
    int b = blockIdx.y;
    int jbase = blockIdx.x * 2048;
    int t = threadIdx.x;
    float inv = 1.0f / row_sum[b];
    float pg = pgen_ws[b];
#pragma unroll
    for (int i = 0; i < 8; i++) {
        int j = jbase + i * 256 + t;
        if (j < VP_) {
            if (j < V_) {
                float p = out_pvocab[(size_t)b * V_ + j] * inv;
                out_pvocab[(size_t)b * V_ + j] = p;
                out_pfinal[(size_t)b * VP_ + j] = p * pg;
            } else {
                out_pfinal[(size_t)b * VP_ + j] = 0.0f;
            }
        }
    }
}

// ---------- K7: scatter-add (1-p_gen)*att_dist into p_final ----------
__global__ __launch_bounds__(256) void k_scatter(
    const int* __restrict__ fiv, const float* __restrict__ attd_ws,
    const float* __restrict__ pgen_ws, float* __restrict__ out_pfinal) {
    int b = blockIdx.x;
    int t = threadIdx.x;
    float omg = 1.0f - pgen_ws[b];
    for (int s = t; s < S_; s += 256) {
        int idx = fiv[b * S_ + s];
        float val = omg * attd_ws[b * S_ + s];
        atomicAdd(&out_pfinal[(size_t)b * VP_ + idx], val);
    }
}

extern "C" void kernel_launch(void* const* d_in, const int* in_sizes, int n_in,
                              void* d_out, int out_size, void* d_ws, size_t ws_size,
                              hipStream_t stream) {
    const int* token = (const int*)d_in[0];
    const float* hprev = (const float*)d_in[1];
    const float* enc = (const float*)d_in[2];
    const int* fiv = (const int*)d_in[3];
    const float* emb = (const float*)d_in[4];
    const float* w_ih = (const float*)d_in[5];
    const float* w_hh = (const float*)d_in[6];
    const float* b_ih = (const float*)d_in[7];
    const float* b_hh = (const float*)d_in[8];
    const float* w_h = (const float*)d_in[9];
    const float* w_s = (const float*)d_in[10];
    const float* att_bias = (const float*)d_in[11];
    const float* attn_v = (const float*)d_in[12];
    const float* gen_w = (const float*)d_in[13];
    const float* gen_b = (const float*)d_in[14];
    const float* outh_w = (const float*)d_in[15];
    const float* outh_b = (const float*)d_in[16];
    const float* outv_w = (const float*)d_in[17];
    const float* outv_b = (const float*)d_in[18];

    float* out = (float*)d_out;
    float* out_hnew = out;                                    // B*H
    float* out_pfinal = out + (size_t)B_ * H_;                // B*VP
    float* out_pgen = out_pfinal + (size_t)B_ * VP_;          // B
    float* out_pvocab = out_pgen + B_;                        // B*V
    float* out_attd = out_pvocab + (size_t)B_ * V_;           // B*S

    float* wsf = (float*)d_ws;
    float* x_ws = wsf;                       // 16384
    float* hnew_ws = wsf + 16384;            // 32768
    float* attd_ws = wsf + 49152;            // 51200
    float* ctx_ws = wsf + 100352;            // 32768
    float* hidden_ws = wsf + 133120;         // 16384
    float* pgen_ws = wsf + 149504;           // 128
    float* row_sum = wsf + 149632;           // 128
    float* sc_ws = wsf + 149760;             // 51200
    float* ml_ws = wsf + 200960;             // 2048
    float* ctxp_ws = wsf + 203008;           // 262144
    float* gi_ws = wsf + 465152;             // 98304
    float* gh_ws = wsf + 563456;             // 98304  (total ~2.65 MB)

    k_gates<<<24, 256, 0, stream>>>(token, emb, hprev, w_ih, w_hh, x_ws, gi_ws, gh_ws);
    k_gru_nl<<<B_, 256, 0, stream>>>(gi_ws, gh_ws, b_ih, b_hh, hprev,
                                     hnew_ws, row_sum, out_hnew);
    k_attn_scores<<<dim3(NC_, B_), 256, 0, stream>>>(enc, w_h, w_s, att_bias, attn_v,
                                                     hnew_ws, sc_ws, ml_ws, ctxp_ws);
    k_attn_combine<<<B_, 256, 0, stream>>>(sc_ws, ml_ws, ctxp_ws,
                                           attd_ws, ctx_ws, out_attd);
    k_outh<<<B_, 128, 0, stream>>>(outh_w, outh_b, gen_w, gen_b,
                                   hnew_ws, ctx_ws, x_ws, hidden_ws, pgen_ws, out_pgen);
    k_vocab_mfma<<<782, 256, 0, stream>>>(outv_w, outv_b, hidden_ws, out_pvocab, row_sum);
    k_final<<<dim3(25, B_), 256, 0, stream>>>(row_sum, pgen_ws, out_pfinal, out_pvocab);
    k_scatter<<<B_, 256, 0, stream>>>(fiv, attd_ws, pgen_ws, out_pfinal);
}

// Round 6
// 233.149 us; speedup vs baseline: 1.5534x; 1.0874x over previous
//
#include <hip/hip_runtime.h>
#include <hip/hip_bf16.h>

// AttnDecoderRNN. B=128, S=400, H=256, E=128, V=50000, PAD=250.
// Inputs: float32 + int32. Outputs: float32 concat:
//   h_new(B*H), p_final(B*VP), p_gen(B), p_vocab(B*V), att_dist(B*S)
// 5 dispatches: gates MFMA -> mega(per-b: GRU-nl + online-attn + outh + pgen)
//               -> vocab MFMA -> final normalize -> scatter.

#define B_ 128
#define S_ 400
#define H_ 256
#define E_ 128
#define V_ 50000
#define PAD_ 250
#define VP_ (V_ + PAD_)
#define NSUM_ 16         // striped row_sum copies (atomic contention /16)

typedef unsigned short ushort_t;
typedef __attribute__((ext_vector_type(8))) short bf16x8;
typedef __attribute__((ext_vector_type(4))) float f32x4;

__device__ __forceinline__ unsigned short f2bfu(float f) {
    __hip_bfloat16 h = __float2bfloat16(f);  // RNE
    union { __hip_bfloat16 h; unsigned short u; } c;
    c.h = h;
    return c.u;
}

__device__ __forceinline__ float sigmoid_fast(float x) {
    return 1.0f / (1.0f + __expf(-x));
}

__device__ __forceinline__ float tanh_fast(float x) {
    return 1.0f - 2.0f / (__expf(2.0f * x) + 1.0f);
}

__device__ __forceinline__ float waveReduceSumAll(float v) {
#pragma unroll
    for (int off = 1; off < 64; off <<= 1) v += __shfl_xor(v, off, 64);
    return v;
}

// ---------- K1: GRU gates GEMM via MFMA: gi = x@w_ih^T, gh = h@w_hh^T ----------
// Grid 24 x 256 (96 v-tile-waves). A=[x(128)|h(256)] bf16 in LDS.
#define XH_PITCH 392   // 384+8 shorts; rows 16B-aligned; 2-way bank alias (free)
__global__ __launch_bounds__(256) void k_gates(
    const int* __restrict__ token, const float* __restrict__ emb,
    const float* __restrict__ hprev,
    const float* __restrict__ w_ih, const float* __restrict__ w_hh,
    float* __restrict__ gi_ws, float* __restrict__ gh_ws) {
    __shared__ ushort_t xh[B_ * XH_PITCH];   // 100352 B
    __shared__ int toks[B_];
    int t = threadIdx.x;
    if (t < B_) toks[t] = token[t];
    __syncthreads();
#pragma unroll
    for (int i = 0; i < 16; i++) {            // x gather: 128 x 32 float4
        int fidx = i * 256 + t;
        int b = fidx >> 5, k4 = fidx & 31;
        float4 q = *(const float4*)(emb + (size_t)toks[b] * E_ + k4 * 4);
        ushort4 u;
        u.x = f2bfu(q.x); u.y = f2bfu(q.y); u.z = f2bfu(q.z); u.w = f2bfu(q.w);
        *(ushort4*)&xh[b * XH_PITCH + k4 * 4] = u;
    }
#pragma unroll
    for (int i = 0; i < 32; i++) {            // h: 128 x 64 float4
        int fidx = i * 256 + t;
        int b = fidx >> 6, k4 = fidx & 63;
        float4 q = *(const float4*)(hprev + (size_t)b * H_ + k4 * 4);
        ushort4 u;
        u.x = f2bfu(q.x); u.y = f2bfu(q.y); u.z = f2bfu(q.z); u.w = f2bfu(q.w);
        *(ushort4*)&xh[b * XH_PITCH + 128 + k4 * 4] = u;
    }
    __syncthreads();

    int wave = t >> 6, lane = t & 63, lm = lane & 15, quad = lane >> 4;
    int vt = blockIdx.x * 4 + wave;          // 0..95
    bool isIH = vt < 48;
    int n0 = (isIH ? vt : vt - 48) * 16;
    const float* wbase = isIH ? w_ih : w_hh;
    int K = isIH ? E_ : H_;
    int aoff = isIH ? 0 : 128;
    float* gout = isIH ? gi_ws : gh_ws;
    int v = n0 + lm;
    const float* wrow = wbase + (size_t)v * K;

    f32x4 acc[8];
#pragma unroll
    for (int bt = 0; bt < 8; bt++) acc[bt] = (f32x4){0.f, 0.f, 0.f, 0.f};

    for (int kc = 0; kc < (K >> 5); kc++) {
        int k0 = kc * 32 + quad * 8;
        float4 w0 = *(const float4*)(wrow + k0);
        float4 w1 = *(const float4*)(wrow + k0 + 4);
        bf16x8 bf;
        bf[0] = (short)f2bfu(w0.x); bf[1] = (short)f2bfu(w0.y);
        bf[2] = (short)f2bfu(w0.z); bf[3] = (short)f2bfu(w0.w);
        bf[4] = (short)f2bfu(w1.x); bf[5] = (short)f2bfu(w1.y);
        bf[6] = (short)f2bfu(w1.z); bf[7] = (short)f2bfu(w1.w);
#pragma unroll
        for (int bt = 0; bt < 8; bt++) {
            bf16x8 af = *(const bf16x8*)&xh[(bt * 16 + lm) * XH_PITCH + aoff + k0];
            acc[bt] = __builtin_amdgcn_mfma_f32_16x16x32_bf16(af, bf, acc[bt], 0, 0, 0);
        }
    }
#pragma unroll
    for (int bt = 0; bt < 8; bt++)
#pragma unroll
        for (int r = 0; r < 4; r++) {
            int b = bt * 16 + quad * 4 + r;
            gout[(size_t)b * 768 + v] = acc[bt][r];
        }
}

// ---------- K2: mega per-b kernel: GRU-nl + online attn + combine + outh + pgen ----
// Grid 128 x 1024 (16 waves). Single pass over enc row-block (400 KB/b).
__global__ __launch_bounds__(1024) void k_mega(
    const float* __restrict__ gi_ws, const float* __restrict__ gh_ws,
    const float* __restrict__ b_ih, const float* __restrict__ b_hh,
    const float* __restrict__ hprev,
    const int* __restrict__ token, const float* __restrict__ emb,
    const float* __restrict__ enc,
    const float* __restrict__ w_h, const float* __restrict__ w_s,
    const float* __restrict__ att_bias, const float* __restrict__ attn_v,
    const float* __restrict__ outh_w, const float* __restrict__ outh_b,
    const float* __restrict__ gen_w, const float* __restrict__ gen_b,
    float* __restrict__ out_hnew, float* __restrict__ out_attd,
    float* __restrict__ out_pgen,
    float* __restrict__ attd_ws, float* __restrict__ hidden_ws,
    float* __restrict__ pgen_ws, float* __restrict__ row_sum16) {
    int b = blockIdx.x;
    int t = threadIdx.x;
    int wave = t >> 6, lane = t & 63;
    __shared__ float hn_s[H_], whs[H_], vs[H_], cs[H_];
    __shared__ float sc[S_];
    __shared__ float cmerge[H_];
    __shared__ float mred[16], lred[16];
    __shared__ float dc[2 * H_ + E_];
    __shared__ float r2[16];

    // phase 0: zero row_sum16 (block 0), h_new, attention constants
    if (b == 0) {
        for (int i = t; i < NSUM_ * B_; i += 1024) row_sum16[i] = 0.0f;
    }
    if (t < H_) {
        float ir = gi_ws[(size_t)b * 768 + t] + b_ih[t];
        float iz = gi_ws[(size_t)b * 768 + 256 + t] + b_ih[256 + t];
        float in_ = gi_ws[(size_t)b * 768 + 512 + t] + b_ih[512 + t];
        float hr = gh_ws[(size_t)b * 768 + t] + b_hh[t];
        float hz = gh_ws[(size_t)b * 768 + 256 + t] + b_hh[256 + t];
        float hn = gh_ws[(size_t)b * 768 + 512 + t] + b_hh[512 + t];
        float hp = hprev[(size_t)b * H_ + t];
        float r = sigmoid_fast(ir + hr);
        float z = sigmoid_fast(iz + hz);
        float n = tanh_fast(in_ + r * hn);
        float h = (1.0f - z) * n + z * hp;
        hn_s[t] = h;
        out_hnew[(size_t)b * H_ + t] = h;
        whs[t] = w_h[t];
        vs[t] = attn_v[t];
        cs[t] = w_s[t] * h + att_bias[0];
        cmerge[t] = 0.0f;
    }
    __syncthreads();

    // phase 1: online-softmax scores + weighted context partials (one enc pass)
    int h0 = lane * 4;
    float m_w = -1e30f, l_w = 0.0f;
    float cx0 = 0.f, cx1 = 0.f, cx2 = 0.f, cx3 = 0.f;
    for (int s = wave; s < S_; s += 16) {
        float4 u = *(const float4*)(enc + ((size_t)(b * S_ + s)) * H_ + h0);
        float p = vs[h0 + 0] * tanh_fast(whs[h0 + 0] * u.x + cs[h0 + 0])
                + vs[h0 + 1] * tanh_fast(whs[h0 + 1] * u.y + cs[h0 + 1])
                + vs[h0 + 2] * tanh_fast(whs[h0 + 2] * u.z + cs[h0 + 2])
                + vs[h0 + 3] * tanh_fast(whs[h0 + 3] * u.w + cs[h0 + 3]);
        p = waveReduceSumAll(p);
        if (lane == 0) sc[s] = p;
        float mn = fmaxf(m_w, p);
        float scale = __expf(m_w - mn);
        float w = __expf(p - mn);
        cx0 = cx0 * scale + w * u.x;
        cx1 = cx1 * scale + w * u.y;
        cx2 = cx2 * scale + w * u.z;
        cx3 = cx3 * scale + w * u.w;
        l_w = l_w * scale + w;
        m_w = mn;
    }
    if (lane == 0) mred[wave] = m_w;
    __syncthreads();

    // phase 2: combine 16 waves
    float M = -1e30f;
#pragma unroll
    for (int wv = 0; wv < 16; wv++) M = fmaxf(M, mred[wv]);
    float wf = __expf(m_w - M);
    if (lane == 0) lred[wave] = l_w * wf;
    atomicAdd(&cmerge[h0 + 0], cx0 * wf);
    atomicAdd(&cmerge[h0 + 1], cx1 * wf);
    atomicAdd(&cmerge[h0 + 2], cx2 * wf);
    atomicAdd(&cmerge[h0 + 3], cx3 * wf);
    __syncthreads();
    float L = 0.0f;
#pragma unroll
    for (int wv = 0; wv < 16; wv++) L += lred[wv];
    float invL = 1.0f / L;

    // phase 3: att_dist
    if (t < S_) {
        float a = __expf(sc[t] - M) * invL;
        attd_ws[b * S_ + t] = a;
        out_attd[(size_t)b * S_ + t] = a;
    }
    // phase 4: dec_ctx = [h_new | ctx | x]
    if (t < H_) {
        dc[t] = hn_s[t];
        dc[H_ + t] = cmerge[t] * invL;
    }
    if (t < E_) dc[2 * H_ + t] = emb[(size_t)token[b] * E_ + t];
    __syncthreads();

    // phase 5: hidden[r] = dot(outh_w[r, 0:512], dc[0:512]) + outh_b[r], 8 thr/row
    {
        int r = t >> 3, sub = t & 7;
        const float* wrow = outh_w + (size_t)r * (2 * H_);
        float acc = 0.0f;
#pragma unroll
        for (int i = 0; i < 16; i++) {
            int k = i * 32 + sub * 4;
            float4 q = *(const float4*)(wrow + k);
            acc += dc[k] * q.x + dc[k + 1] * q.y + dc[k + 2] * q.z + dc[k + 3] * q.w;
        }
        acc += __shfl_down(acc, 4, 64);
        acc += __shfl_down(acc, 2, 64);
        acc += __shfl_down(acc, 1, 64);
        if (sub == 0) hidden_ws[(size_t)b * E_ + r] = acc + outh_b[r];
    }
    // phase 6: p_gen
    float pp = (t < 2 * H_ + E_) ? dc[t] * gen_w[t] : 0.0f;
    pp = waveReduceSumAll(pp);
    if (lane == 0) r2[wave] = pp;
    __syncthreads();
    if (t == 0) {
        float g = 0.0f;
#pragma unroll
        for (int wv = 0; wv < 16; wv++) g += r2[wv];
        g = sigmoid_fast(g + gen_b[0]);
        pgen_ws[b] = g;
        out_pgen[b] = g;
    }
}

// ---------- K3: vocab GEMM (MFMA bf16) -> exp (f32 into p_vocab) + striped row sums --
#define VT_TOTAL (V_ / 16)          // 3125
#define HID_PITCH 136               // 128+8 shorts
__global__ __launch_bounds__(256) void k_vocab_mfma(
    const float* __restrict__ outv_w, const float* __restrict__ outv_b,
    const float* __restrict__ hidden_ws,
    float* __restrict__ out_pvocab, float* __restrict__ row_sum16) {
    __shared__ ushort_t hid[B_ * HID_PITCH];   // 34816 B
    __shared__ float rsum[B_];
    int t = threadIdx.x;

    const float4* h4 = (const float4*)hidden_ws;
#pragma unroll
    for (int i = 0; i < 16; i++) {
        int fidx = i * 256 + t;
        float4 q = h4[fidx];
        int row = fidx >> 5;
        int col = (fidx & 31) << 2;
        ushort4 u;
        u.x = f2bfu(q.x); u.y = f2bfu(q.y); u.z = f2bfu(q.z); u.w = f2bfu(q.w);
        *(ushort4*)&hid[row * HID_PITCH + col] = u;
    }
    if (t < B_) rsum[t] = 0.0f;
    __syncthreads();

    int wave = t >> 6, lane = t & 63, lm = lane & 15, quad = lane >> 4;
    int vt = blockIdx.x * 4 + wave;

    if (vt < VT_TOTAL) {
        int v = vt * 16 + lm;
        const float* wrow = outv_w + (size_t)v * E_;

        f32x4 acc[8];
#pragma unroll
        for (int bt = 0; bt < 8; bt++) acc[bt] = (f32x4){0.f, 0.f, 0.f, 0.f};

#pragma unroll
        for (int kc = 0; kc < 4; kc++) {
            int k0 = kc * 32 + quad * 8;
            float4 w0 = *(const float4*)(wrow + k0);
            float4 w1 = *(const float4*)(wrow + k0 + 4);
            bf16x8 bf;
            bf[0] = (short)f2bfu(w0.x); bf[1] = (short)f2bfu(w0.y);
            bf[2] = (short)f2bfu(w0.z); bf[3] = (short)f2bfu(w0.w);
            bf[4] = (short)f2bfu(w1.x); bf[5] = (short)f2bfu(w1.y);
            bf[6] = (short)f2bfu(w1.z); bf[7] = (short)f2bfu(w1.w);
#pragma unroll
            for (int bt = 0; bt < 8; bt++) {
                bf16x8 af = *(const bf16x8*)&hid[(bt * 16 + lm) * HID_PITCH + k0];
                acc[bt] = __builtin_amdgcn_mfma_f32_16x16x32_bf16(af, bf, acc[bt], 0, 0, 0);
            }
        }

        float bias = outv_b[v];
#pragma unroll
        for (int bt = 0; bt < 8; bt++) {
#pragma unroll
            for (int r = 0; r < 4; r++) {
                int b = bt * 16 + quad * 4 + r;
                float e = __expf(fminf(acc[bt][r] + bias, 60.0f));
                out_pvocab[(size_t)b * V_ + v] = e;
                float s = e;
                s += __shfl_xor(s, 1);
                s += __shfl_xor(s, 2);
                s += __shfl_xor(s, 4);
                s += __shfl_xor(s, 8);
                if (lm == 0) atomicAdd(&rsum[b], s);
            }
        }
    }
    __syncthreads();
    if (t < B_) atomicAdd(&row_sum16[(blockIdx.x & (NSUM_ - 1)) * B_ + t], rsum[t]);
}

// ---------- K4: normalize in-place: p_vocab, p_final dense + PAD zeros ----------
__global__ __launch_bounds__(256) void k_final(
    const float* __restrict__ row_sum16, const float* __restrict__ pgen_ws,
    float* __restrict__ out_pfinal, float* __restrict__ out_pvocab) {
    int b = blockIdx.y;
    int jbase = blockIdx.x * 2048;
    int t = threadIdx.x;
    float rs = 0.0f;
#pragma unroll
    for (int i = 0; i < NSUM_; i++) rs += row_sum16[i * B_ + b];
    float inv = 1.0f / rs;
    float pg = pgen_ws[b];
#pragma unroll
    for (int i = 0; i < 8; i++) {
        int j = jbase + i * 256 + t;
        if (j < VP_) {
            if (j < V_) {
                float p = out_pvocab[(size_t)b * V_ + j] * inv;
                out_pvocab[(size_t)b * V_ + j] = p;
                out_pfinal[(size_t)b * VP_ + j] = p * pg;
            } else {
                out_pfinal[(size_t)b * VP_ + j] = 0.0f;
            }
        }
    }
}

// ---------- K5: scatter-add (1-p_gen)*att_dist into p_final ----------
__global__ __launch_bounds__(256) void k_scatter(
    const int* __restrict__ fiv, const float* __restrict__ attd_ws,
    const float* __restrict__ pgen_ws, float* __restrict__ out_pfinal) {
    int b = blockIdx.x;
    int t = threadIdx.x;
    float omg = 1.0f - pgen_ws[b];
    for (int s = t; s < S_; s += 256) {
        int idx = fiv[b * S_ + s];
        float val = omg * attd_ws[b * S_ + s];
        atomicAdd(&out_pfinal[(size_t)b * VP_ + idx], val);
    }
}

extern "C" void kernel_launch(void* const* d_in, const int* in_sizes, int n_in,
                              void* d_out, int out_size, void* d_ws, size_t ws_size,
                              hipStream_t stream) {
    const int* token = (const int*)d_in[0];
    const float* hprev = (const float*)d_in[1];
    const float* enc = (const float*)d_in[2];
    const int* fiv = (const int*)d_in[3];
    const float* emb = (const float*)d_in[4];
    const float* w_ih = (const float*)d_in[5];
    const float* w_hh = (const float*)d_in[6];
    const float* b_ih = (const float*)d_in[7];
    const float* b_hh = (const float*)d_in[8];
    const float* w_h = (const float*)d_in[9];
    const float* w_s = (const float*)d_in[10];
    const float* att_bias = (const float*)d_in[11];
    const float* attn_v = (const float*)d_in[12];
    const float* gen_w = (const float*)d_in[13];
    const float* gen_b = (const float*)d_in[14];
    const float* outh_w = (const float*)d_in[15];
    const float* outh_b = (const float*)d_in[16];
    const float* outv_w = (const float*)d_in[17];
    const float* outv_b = (const float*)d_in[18];

    float* out = (float*)d_out;
    float* out_hnew = out;                                    // B*H
    float* out_pfinal = out + (size_t)B_ * H_;                // B*VP
    float* out_pgen = out_pfinal + (size_t)B_ * VP_;          // B
    float* out_pvocab = out_pgen + B_;                        // B*V
    float* out_attd = out_pvocab + (size_t)B_ * V_;           // B*S

    float* wsf = (float*)d_ws;
    float* gi_ws = wsf;                      // 98304
    float* gh_ws = wsf + 98304;              // 98304
    float* attd_ws = wsf + 196608;           // 51200
    float* hidden_ws = wsf + 247808;         // 16384
    float* pgen_ws = wsf + 264192;           // 128
    float* row_sum16 = wsf + 264320;         // 2048   (total ~1.07 MB)

    k_gates<<<24, 256, 0, stream>>>(token, emb, hprev, w_ih, w_hh, gi_ws, gh_ws);
    k_mega<<<B_, 1024, 0, stream>>>(gi_ws, gh_ws, b_ih, b_hh, hprev, token, emb,
                                    enc, w_h, w_s, att_bias, attn_v,
                                    outh_w, outh_b, gen_w, gen_b,
                                    out_hnew, out_attd, out_pgen,
                                    attd_ws, hidden_ws, pgen_ws, row_sum16);
    k_vocab_mfma<<<782, 256, 0, stream>>>(outv_w, outv_b, hidden_ws, out_pvocab, row_sum16);
    k_final<<<dim3(25, B_), 256, 0, stream>>>(row_sum16, pgen_ws, out_pfinal, out_pvocab);
    k_scatter<<<B_, 256, 0, stream>>>(fiv, attd_ws, pgen_ws, out_pfinal);
}

// Round 7
// 225.723 us; speedup vs baseline: 1.6045x; 1.0329x over previous
//
#include <hip/hip_runtime.h>
#include <hip/hip_bf16.h>

// AttnDecoderRNN. B=128, S=400, H=256, E=128, V=50000, PAD=250.
// Inputs: float32 + int32. Outputs: float32 concat:
//   h_new(B*H), p_final(B*VP), p_gen(B), p_vocab(B*V), att_dist(B*S)
// 6 dispatches: gates MFMA -> attn(chunked, inline GRU-nl) -> combine(+outh+pgen)
//               -> vocab MFMA -> final normalize -> scatter.

#define B_ 128
#define S_ 400
#define H_ 256
#define E_ 128
#define V_ 50000
#define PAD_ 250
#define VP_ (V_ + PAD_)
#define NC_ 8            // attention S-chunks
#define CS_ (S_ / NC_)   // 50
#define NSUM_ 16         // striped row_sum copies

typedef unsigned short ushort_t;
typedef __attribute__((ext_vector_type(8))) short bf16x8;
typedef __attribute__((ext_vector_type(4))) float f32x4;

__device__ __forceinline__ unsigned short f2bfu(float f) {
    __hip_bfloat16 h = __float2bfloat16(f);  // RNE
    union { __hip_bfloat16 h; unsigned short u; } c;
    c.h = h;
    return c.u;
}

__device__ __forceinline__ float sigmoid_fast(float x) {
    return 1.0f / (1.0f + __expf(-x));
}

__device__ __forceinline__ float tanh_fast(float x) {
    return 1.0f - 2.0f / (__expf(2.0f * x) + 1.0f);
}

__device__ __forceinline__ float waveReduceSumAll(float v) {
#pragma unroll
    for (int off = 1; off < 64; off <<= 1) v += __shfl_xor(v, off, 64);
    return v;
}

// ---------- K1: GRU gates GEMM via MFMA: gi = x@w_ih^T, gh = h@w_hh^T ----------
// Blocks 0..11: IH tiles (stage x only, pitch 136). Blocks 12..23: HH (h only, pitch 264).
__global__ __launch_bounds__(256) void k_gates(
    const int* __restrict__ token, const float* __restrict__ emb,
    const float* __restrict__ hprev,
    const float* __restrict__ w_ih, const float* __restrict__ w_hh,
    float* __restrict__ gi_ws, float* __restrict__ gh_ws) {
    __shared__ ushort_t xh[B_ * 264];   // 67584 B (max of both layouts)
    __shared__ int toks[B_];
    int t = threadIdx.x;
    bool isIH = blockIdx.x < 12;
    if (isIH) {
        if (t < B_) toks[t] = token[t];
        __syncthreads();
#pragma unroll
        for (int i = 0; i < 16; i++) {            // x gather: 128 x 32 float4
            int fidx = i * 256 + t;
            int b = fidx >> 5, k4 = fidx & 31;
            float4 q = *(const float4*)(emb + (size_t)toks[b] * E_ + k4 * 4);
            ushort4 u;
            u.x = f2bfu(q.x); u.y = f2bfu(q.y); u.z = f2bfu(q.z); u.w = f2bfu(q.w);
            *(ushort4*)&xh[b * 136 + k4 * 4] = u;
        }
    } else {
#pragma unroll
        for (int i = 0; i < 32; i++) {            // h: 128 x 64 float4
            int fidx = i * 256 + t;
            int b = fidx >> 6, k4 = fidx & 63;
            float4 q = *(const float4*)(hprev + (size_t)b * H_ + k4 * 4);
            ushort4 u;
            u.x = f2bfu(q.x); u.y = f2bfu(q.y); u.z = f2bfu(q.z); u.w = f2bfu(q.w);
            *(ushort4*)&xh[b * 264 + k4 * 4] = u;
        }
    }
    __syncthreads();

    int wave = t >> 6, lane = t & 63, lm = lane & 15, quad = lane >> 4;
    int tile = (isIH ? blockIdx.x : blockIdx.x - 12) * 4 + wave;   // 0..47
    int v = tile * 16 + lm;
    int K = isIH ? E_ : H_;
    int pitch = isIH ? 136 : 264;
    const float* wrow = (isIH ? w_ih : w_hh) + (size_t)v * K;
    float* gout = isIH ? gi_ws : gh_ws;

    f32x4 acc[8];
#pragma unroll
    for (int bt = 0; bt < 8; bt++) acc[bt] = (f32x4){0.f, 0.f, 0.f, 0.f};

    for (int kc = 0; kc < (K >> 5); kc++) {
        int k0 = kc * 32 + quad * 8;
        float4 w0 = *(const float4*)(wrow + k0);
        float4 w1 = *(const float4*)(wrow + k0 + 4);
        bf16x8 bf;
        bf[0] = (short)f2bfu(w0.x); bf[1] = (short)f2bfu(w0.y);
        bf[2] = (short)f2bfu(w0.z); bf[3] = (short)f2bfu(w0.w);
        bf[4] = (short)f2bfu(w1.x); bf[5] = (short)f2bfu(w1.y);
        bf[6] = (short)f2bfu(w1.z); bf[7] = (short)f2bfu(w1.w);
#pragma unroll
        for (int bt = 0; bt < 8; bt++) {
            bf16x8 af = *(const bf16x8*)&xh[(bt * 16 + lm) * pitch + k0];
            acc[bt] = __builtin_amdgcn_mfma_f32_16x16x32_bf16(af, bf, acc[bt], 0, 0, 0);
        }
    }
#pragma unroll
    for (int bt = 0; bt < 8; bt++)
#pragma unroll
        for (int r = 0; r < 4; r++) {
            int b = bt * 16 + quad * 4 + r;
            gout[(size_t)b * 768 + v] = acc[bt][r];
        }
}

// ---------- K2: attention chunk: inline GRU-nl + online-softmax partials ----------
// Grid (NC_, B_) x 256. GRU-nl recomputed per block (cheap); block c==0 writes h_new.
__global__ __launch_bounds__(256) void k_attn(
    const float* __restrict__ gi_ws, const float* __restrict__ gh_ws,
    const float* __restrict__ b_ih, const float* __restrict__ b_hh,
    const float* __restrict__ hprev,
    const float* __restrict__ enc,
    const float* __restrict__ w_h, const float* __restrict__ w_s,
    const float* __restrict__ att_bias, const float* __restrict__ attn_v,
    float* __restrict__ out_hnew,
    float* __restrict__ sc_ws, float* __restrict__ ml_ws, float* __restrict__ ctxp_ws) {
    int c = blockIdx.x, b = blockIdx.y;
    int t = threadIdx.x;
    int wave = t >> 6, lane = t & 63;
    __shared__ float whs[H_], vs[H_], cs[H_], cmerge[H_];
    __shared__ float mred[4], lred[4];

    // GRU nonlinearity for this b (t = h index)
    {
        float ir = gi_ws[(size_t)b * 768 + t] + b_ih[t];
        float iz = gi_ws[(size_t)b * 768 + 256 + t] + b_ih[256 + t];
        float in_ = gi_ws[(size_t)b * 768 + 512 + t] + b_ih[512 + t];
        float hr = gh_ws[(size_t)b * 768 + t] + b_hh[t];
        float hz = gh_ws[(size_t)b * 768 + 256 + t] + b_hh[256 + t];
        float hn = gh_ws[(size_t)b * 768 + 512 + t] + b_hh[512 + t];
        float hp = hprev[(size_t)b * H_ + t];
        float r = sigmoid_fast(ir + hr);
        float z = sigmoid_fast(iz + hz);
        float n = tanh_fast(in_ + r * hn);
        float h = (1.0f - z) * n + z * hp;
        if (c == 0) out_hnew[(size_t)b * H_ + t] = h;
        whs[t] = w_h[t];
        vs[t] = attn_v[t];
        cs[t] = w_s[t] * h + att_bias[0];
        cmerge[t] = 0.0f;
    }
    __syncthreads();

    int h0 = lane * 4;
    float m_w = -1e30f, l_w = 0.0f;
    float cx0 = 0.f, cx1 = 0.f, cx2 = 0.f, cx3 = 0.f;
    for (int si = wave; si < CS_; si += 4) {
        int s = c * CS_ + si;
        float4 u = *(const float4*)(enc + ((size_t)(b * S_ + s)) * H_ + h0);
        float p = vs[h0 + 0] * tanh_fast(whs[h0 + 0] * u.x + cs[h0 + 0])
                + vs[h0 + 1] * tanh_fast(whs[h0 + 1] * u.y + cs[h0 + 1])
                + vs[h0 + 2] * tanh_fast(whs[h0 + 2] * u.z + cs[h0 + 2])
                + vs[h0 + 3] * tanh_fast(whs[h0 + 3] * u.w + cs[h0 + 3]);
        p = waveReduceSumAll(p);
        if (lane == 0) sc_ws[b * S_ + s] = p;
        float mn = fmaxf(m_w, p);
        float scale = __expf(m_w - mn);
        float w = __expf(p - mn);
        cx0 = cx0 * scale + w * u.x;
        cx1 = cx1 * scale + w * u.y;
        cx2 = cx2 * scale + w * u.z;
        cx3 = cx3 * scale + w * u.w;
        l_w = l_w * scale + w;
        m_w = mn;
    }
    if (lane == 0) mred[wave] = m_w;
    __syncthreads();
    float m_c = fmaxf(fmaxf(mred[0], mred[1]), fmaxf(mred[2], mred[3]));
    float wf = __expf(m_w - m_c);
    if (lane == 0) lred[wave] = l_w * wf;
    atomicAdd(&cmerge[h0 + 0], cx0 * wf);
    atomicAdd(&cmerge[h0 + 1], cx1 * wf);
    atomicAdd(&cmerge[h0 + 2], cx2 * wf);
    atomicAdd(&cmerge[h0 + 3], cx3 * wf);
    __syncthreads();
    if (t == 0) {
        ml_ws[(b * NC_ + c) * 2 + 0] = m_c;
        ml_ws[(b * NC_ + c) * 2 + 1] = lred[0] + lred[1] + lred[2] + lred[3];
    }
    ctxp_ws[(size_t)(b * NC_ + c) * H_ + t] = cmerge[t];
}

// ---------- K3: combine chunks -> att_dist, ctx; outh GEMV; p_gen ----------
// Grid B_ x 1024 (16 waves). Also zeroes row_sum16 (block 0).
__global__ __launch_bounds__(1024) void k_combine(
    const float* __restrict__ sc_ws, const float* __restrict__ ml_ws,
    const float* __restrict__ ctxp_ws,
    const float* __restrict__ out_hnew,
    const int* __restrict__ token, const float* __restrict__ emb,
    const float* __restrict__ outh_w, const float* __restrict__ outh_b,
    const float* __restrict__ gen_w, const float* __restrict__ gen_b,
    float* __restrict__ out_attd, float* __restrict__ out_pgen,
    float* __restrict__ attd_ws, float* __restrict__ hidden_ws,
    float* __restrict__ pgen_ws, float* __restrict__ row_sum16) {
    int b = blockIdx.x;
    int t = threadIdx.x;
    int wave = t >> 6, lane = t & 63;
    __shared__ float ml[NC_ * 2];
    __shared__ float dc[2 * H_ + E_];
    __shared__ float r2[16];

    if (b == 0) {
        for (int i = t; i < NSUM_ * B_; i += 1024) row_sum16[i] = 0.0f;
    }
    if (t < NC_ * 2) ml[t] = ml_ws[b * NC_ * 2 + t];
    __syncthreads();
    float M = -1e30f;
#pragma unroll
    for (int c = 0; c < NC_; c++) M = fmaxf(M, ml[2 * c]);
    float L = 0.0f;
#pragma unroll
    for (int c = 0; c < NC_; c++) L += ml[2 * c + 1] * __expf(ml[2 * c] - M);
    float invL = 1.0f / L;

    if (t < S_) {
        float a = __expf(sc_ws[b * S_ + t] - M) * invL;
        attd_ws[b * S_ + t] = a;
        out_attd[(size_t)b * S_ + t] = a;
    }
    if (t < H_) {
        float acc = 0.0f;
#pragma unroll
        for (int c = 0; c < NC_; c++)
            acc += __expf(ml[2 * c] - M) * ctxp_ws[(size_t)(b * NC_ + c) * H_ + t];
        dc[t] = out_hnew[(size_t)b * H_ + t];
        dc[H_ + t] = acc * invL;
    }
    if (t < E_) dc[2 * H_ + t] = emb[(size_t)token[b] * E_ + t];
    __syncthreads();

    // hidden[r] = dot(outh_w[r, 0:512], dc[0:512]) + outh_b[r], 8 thr/row
    {
        int r = t >> 3, sub = t & 7;
        const float* wrow = outh_w + (size_t)r * (2 * H_);
        float acc = 0.0f;
#pragma unroll
        for (int i = 0; i < 16; i++) {
            int k = i * 32 + sub * 4;
            float4 q = *(const float4*)(wrow + k);
            acc += dc[k] * q.x + dc[k + 1] * q.y + dc[k + 2] * q.z + dc[k + 3] * q.w;
        }
        acc += __shfl_down(acc, 4, 64);
        acc += __shfl_down(acc, 2, 64);
        acc += __shfl_down(acc, 1, 64);
        if (sub == 0) hidden_ws[(size_t)b * E_ + r] = acc + outh_b[r];
    }
    // p_gen
    float pp = (t < 2 * H_ + E_) ? dc[t] * gen_w[t] : 0.0f;
    pp = waveReduceSumAll(pp);
    if (lane == 0) r2[wave] = pp;
    __syncthreads();
    if (t == 0) {
        float g = 0.0f;
#pragma unroll
        for (int wv = 0; wv < 16; wv++) g += r2[wv];
        g = sigmoid_fast(g + gen_b[0]);
        pgen_ws[b] = g;
        out_pgen[b] = g;
    }
}

// ---------- K4: vocab GEMM (MFMA bf16) -> exp (f32 into p_vocab) + striped row sums --
#define VT_TOTAL (V_ / 16)          // 3125
#define HID_PITCH 136               // 128+8 shorts
__global__ __launch_bounds__(256) void k_vocab_mfma(
    const float* __restrict__ outv_w, const float* __restrict__ outv_b,
    const float* __restrict__ hidden_ws,
    float* __restrict__ out_pvocab, float* __restrict__ row_sum16) {
    __shared__ ushort_t hid[B_ * HID_PITCH];   // 34816 B
    __shared__ float rsum[B_];
    int t = threadIdx.x;

    const float4* h4 = (const float4*)hidden_ws;
#pragma unroll
    for (int i = 0; i < 16; i++) {
        int fidx = i * 256 + t;
        float4 q = h4[fidx];
        int row = fidx >> 5;
        int col = (fidx & 31) << 2;
        ushort4 u;
        u.x = f2bfu(q.x); u.y = f2bfu(q.y); u.z = f2bfu(q.z); u.w = f2bfu(q.w);
        *(ushort4*)&hid[row * HID_PITCH + col] = u;
    }
    if (t < B_) rsum[t] = 0.0f;
    __syncthreads();

    int wave = t >> 6, lane = t & 63, lm = lane & 15, quad = lane >> 4;
    int vt = blockIdx.x * 4 + wave;

    if (vt < VT_TOTAL) {
        int v = vt * 16 + lm;
        const float* wrow = outv_w + (size_t)v * E_;

        f32x4 acc[8];
#pragma unroll
        for (int bt = 0; bt < 8; bt++) acc[bt] = (f32x4){0.f, 0.f, 0.f, 0.f};

#pragma unroll
        for (int kc = 0; kc < 4; kc++) {
            int k0 = kc * 32 + quad * 8;
            float4 w0 = *(const float4*)(wrow + k0);
            float4 w1 = *(const float4*)(wrow + k0 + 4);
            bf16x8 bf;
            bf[0] = (short)f2bfu(w0.x); bf[1] = (short)f2bfu(w0.y);
            bf[2] = (short)f2bfu(w0.z); bf[3] = (short)f2bfu(w0.w);
            bf[4] = (short)f2bfu(w1.x); bf[5] = (short)f2bfu(w1.y);
            bf[6] = (short)f2bfu(w1.z); bf[7] = (short)f2bfu(w1.w);
#pragma unroll
            for (int bt = 0; bt < 8; bt++) {
                bf16x8 af = *(const bf16x8*)&hid[(bt * 16 + lm) * HID_PITCH + k0];
                acc[bt] = __builtin_amdgcn_mfma_f32_16x16x32_bf16(af, bf, acc[bt], 0, 0, 0);
            }
        }

        float bias = outv_b[v];
#pragma unroll
        for (int bt = 0; bt < 8; bt++) {
#pragma unroll
            for (int r = 0; r < 4; r++) {
                int b = bt * 16 + quad * 4 + r;
                float e = __expf(fminf(acc[bt][r] + bias, 60.0f));
                out_pvocab[(size_t)b * V_ + v] = e;
                float s = e;
                s += __shfl_xor(s, 1);
                s += __shfl_xor(s, 2);
                s += __shfl_xor(s, 4);
                s += __shfl_xor(s, 8);
                if (lm == 0) atomicAdd(&rsum[b], s);
            }
        }
    }
    __syncthreads();
    if (t < B_) atomicAdd(&row_sum16[(blockIdx.x & (NSUM_ - 1)) * B_ + t], rsum[t]);
}

// ---------- K5: normalize in-place: p_vocab, p_final dense + PAD zeros ----------
__global__ __launch_bounds__(256) void k_final(
    const float* __restrict__ row_sum16, const float* __restrict__ pgen_ws,
    float* __restrict__ out_pfinal, float* __restrict__ out_pvocab) {
    int b = blockIdx.y;
    int jbase = blockIdx.x * 2048;
    int t = threadIdx.x;
    float rs = 0.0f;
#pragma unroll
    for (int i = 0; i < NSUM_; i++) rs += row_sum16[i * B_ + b];
    float inv = 1.0f / rs;
    float pg = pgen_ws[b];
#pragma unroll
    for (int i = 0; i < 8; i++) {
        int j = jbase + i * 256 + t;
        if (j < VP_) {
            if (j < V_) {
                float p = out_pvocab[(size_t)b * V_ + j] * inv;
                out_pvocab[(size_t)b * V_ + j] = p;
                out_pfinal[(size_t)b * VP_ + j] = p * pg;
            } else {
                out_pfinal[(size_t)b * VP_ + j] = 0.0f;
            }
        }
    }
}

// ---------- K6: scatter-add (1-p_gen)*att_dist into p_final ----------
__global__ __launch_bounds__(256) void k_scatter(
    const int* __restrict__ fiv, const float* __restrict__ attd_ws,
    const float* __restrict__ pgen_ws, float* __restrict__ out_pfinal) {
    int b = blockIdx.x;
    int t = threadIdx.x;
    float omg = 1.0f - pgen_ws[b];
    for (int s = t; s < S_; s += 256) {
        int idx = fiv[b * S_ + s];
        float val = omg * attd_ws[b * S_ + s];
        atomicAdd(&out_pfinal[(size_t)b * VP_ + idx], val);
    }
}

extern "C" void kernel_launch(void* const* d_in, const int* in_sizes, int n_in,
                              void* d_out, int out_size, void* d_ws, size_t ws_size,
                              hipStream_t stream) {
    const int* token = (const int*)d_in[0];
    const float* hprev = (const float*)d_in[1];
    const float* enc = (const float*)d_in[2];
    const int* fiv = (const int*)d_in[3];
    const float* emb = (const float*)d_in[4];
    const float* w_ih = (const float*)d_in[5];
    const float* w_hh = (const float*)d_in[6];
    const float* b_ih = (const float*)d_in[7];
    const float* b_hh = (const float*)d_in[8];
    const float* w_h = (const float*)d_in[9];
    const float* w_s = (const float*)d_in[10];
    const float* att_bias = (const float*)d_in[11];
    const float* attn_v = (const float*)d_in[12];
    const float* gen_w = (const float*)d_in[13];
    const float* gen_b = (const float*)d_in[14];
    const float* outh_w = (const float*)d_in[15];
    const float* outh_b = (const float*)d_in[16];
    const float* outv_w = (const float*)d_in[17];
    const float* outv_b = (const float*)d_in[18];

    float* out = (float*)d_out;
    float* out_hnew = out;                                    // B*H
    float* out_pfinal = out + (size_t)B_ * H_;                // B*VP
    float* out_pgen = out_pfinal + (size_t)B_ * VP_;          // B
    float* out_pvocab = out_pgen + B_;                        // B*V
    float* out_attd = out_pvocab + (size_t)B_ * V_;           // B*S

    float* wsf = (float*)d_ws;
    float* gi_ws = wsf;                      // 98304
    float* gh_ws = wsf + 98304;              // 98304
    float* attd_ws = wsf + 196608;           // 51200
    float* hidden_ws = wsf + 247808;         // 16384
    float* pgen_ws = wsf + 264192;           // 128
    float* row_sum16 = wsf + 264320;         // 2048
    float* sc_ws = wsf + 266368;             // 51200
    float* ml_ws = wsf + 317568;             // 2048
    float* ctxp_ws = wsf + 319616;           // 262144  (total ~2.3 MB)

    k_gates<<<24, 256, 0, stream>>>(token, emb, hprev, w_ih, w_hh, gi_ws, gh_ws);
    k_attn<<<dim3(NC_, B_), 256, 0, stream>>>(gi_ws, gh_ws, b_ih, b_hh, hprev,
                                              enc, w_h, w_s, att_bias, attn_v,
                                              out_hnew, sc_ws, ml_ws, ctxp_ws);
    k_combine<<<B_, 1024, 0, stream>>>(sc_ws, ml_ws, ctxp_ws, out_hnew, token, emb,
                                       outh_w, outh_b, gen_w, gen_b,
                                       out_attd, out_pgen,
                                       attd_ws, hidden_ws, pgen_ws, row_sum16);
    k_vocab_mfma<<<782, 256, 0, stream>>>(outv_w, outv_b, hidden_ws, out_pvocab, row_sum16);
    k_final<<<dim3(25, B_), 256, 0, stream>>>(row_sum16, pgen_ws, out_pfinal, out_pvocab);
    k_scatter<<<B_, 256, 0, stream>>>(fiv, attd_ws, pgen_ws, out_pfinal);
}